// Round 5
// baseline (259.356 us; speedup 1.0000x reference)
//
#include <hip/hip_runtime.h>
#include <stdint.h>

#define N_EXPERTS 8
#define IN_DIM    1024
#define OUT_DIM   1024
#define N_TOKENS  16384
#define S_SLOTS   (N_TOKENS * 2)

// ---- main 256x256 pipelined GEMM geometry ----
#define BM   256
#define BN   256
#define BK   32                    // bf16 K-cols per stage tile
#define NKT  (IN_DIM / BK)         // 32 K-tiles
#define MT   136                   // sum ceil(cnt_e/256) <= 128 + 8
#define NG   (OUT_DIM / BN)        // 4
#define NXCD 8
#define CPX  (MT / NXCD)           // 17 exact -> bijective XCD swizzle
#define ABUF(s) (smem + (s) * 8192)            // 16 KB each (u16 units)
#define BBUF(s) (smem + 24576 + (s) * 8192)    // 16 KB each

// ---- fallback geometry (verified legacy path) ----
#define FBM  128
#define FMT  264

typedef unsigned short u16;
using short4v = __attribute__((ext_vector_type(4))) short;
using short8  = __attribute__((ext_vector_type(8))) short;
using f32x4   = __attribute__((ext_vector_type(4))) float;

__device__ __forceinline__ u16 f2bf(float f) {
  uint32_t x = __builtin_bit_cast(uint32_t, f);
  uint32_t r = x + 0x7fffu + ((x >> 16) & 1u);   // round-to-nearest-even
  return (u16)(r >> 16);
}
__device__ __forceinline__ float bf2f(u16 u) {
  uint32_t x = ((uint32_t)u) << 16;
  return __builtin_bit_cast(float, x);
}

#define GLD_LDS16(g, l) __builtin_amdgcn_global_load_lds(            \
    (const __attribute__((address_space(1))) void*)(g),              \
    (__attribute__((address_space(3))) void*)(l), 16, 0, 0)

// ---------------------------------------------------------------------------
// Shared tile derivation (slots sorted by expert), parametric block-M.
// ---------------------------------------------------------------------------
__device__ __forceinline__ bool derive_tile(const int* eoff_raw, bool is64,
                                            int bx, int bm,
                                            int& expert, int& rs, int& re) {
  int rem = bx, prev = 0;
  expert = -1;
  for (int e = 0; e < N_EXPERTS; ++e) {
    int end = is64 ? eoff_raw[2 * e] : eoff_raw[e];
    int cnt = end - prev;
    int nt  = (cnt + bm - 1) / bm;
    if (expert < 0) {
      if (rem < nt) {
        expert = e;
        rs = prev + rem * bm;
        re = (rs + bm < end) ? (rs + bm) : end;
      } else {
        rem -= nt;
      }
    }
    prev = end;
  }
  return expert >= 0;
}

// ---------------------------------------------------------------------------
// Node 1: fp32->bf16 convert of X and W, PLUS zeroing of straddle-pair token
// rows (odd 256-tile starts) so the GEMM can atomicAdd edge contributions.
// ---------------------------------------------------------------------------
__global__ __launch_bounds__(256) void convert_zero(
    const float* __restrict__ X, const float* __restrict__ W,
    u16* __restrict__ Xb, u16* __restrict__ Wb,
    const int* __restrict__ eoff_raw,
    float* __restrict__ out,
    int xblocks, int wblocks, int xn8, int wn8) {
  int bx = blockIdx.x;
  if (bx < xblocks + wblocks) {
    const float* src; u16* dst; int i, n8;
    if (bx < xblocks) { i = bx * 256 + threadIdx.x; src = X; dst = Xb; n8 = xn8; }
    else { i = (bx - xblocks) * 256 + threadIdx.x; src = W; dst = Wb; n8 = wn8; }
    if (i >= n8) return;
    const f32x4* s = (const f32x4*)src + (size_t)i * 2;
    f32x4 v0 = s[0], v1 = s[1];
    short8 o;
#pragma unroll
    for (int j = 0; j < 4; ++j) {
      o[j]     = (short)f2bf(v0[j]);
      o[4 + j] = (short)f2bf(v1[j]);
    }
    *(short8*)(dst + (size_t)i * 8) = o;
  } else {
    int bx2 = bx - xblocks - wblocks;
    const bool is64 = (eoff_raw[7] != S_SLOTS);
    int expert, rs, re;
    if (!derive_tile(eoff_raw, is64, bx2, BM, expert, rs, re)) return;
    if (rs & 1) {
      f32x4 z = (f32x4){0.f, 0.f, 0.f, 0.f};
      *(f32x4*)(out + (size_t)(rs >> 1) * OUT_DIM + threadIdx.x * 4) = z;
    }
  }
}

// ---------------------------------------------------------------------------
// Node 2: 256x256 grouped GEMM, 3-stage software pipeline (T3+T4 proper):
//  - BK=32 K-tiles, 3 LDS stage buffers (96 KB staging; 128 KB block for Cs)
//  - per tile: issue 4 global_load_lds for tile kt+2, then s_waitcnt
//    vmcnt(8) -- only the 2-tiles-ahead loads remain outstanding, so tile
//    kt's data is guaranteed landed with ~2 tiles of issue-to-use distance.
//    NEVER vmcnt(0) inside the loop (T4, m218).
//  - source-pre-swizzled staging (linear LDS dest, rule 21/m173): physical
//    16B chunk cphys of a row holds logical chunk cphys^(row&3); frag
//    ds_read_b128 applies the same XOR (2-way bank alias = free, m136).
//  - 8 waves (2M x 4N), per-wave 128x64 output; lgkmcnt(0)+sched_barrier
//    (rule 18) + setprio(1) around the 32-MFMA cluster (T5).
// Epilogue: proven LDS repack + gate-combine pairs + atomicAdd edges.
// ---------------------------------------------------------------------------
__global__ __launch_bounds__(512, 2) void moe_gemm_256(
    const u16*   __restrict__ Xb,       // [N_TOKENS, IN_DIM] bf16 (ws)
    const u16*   __restrict__ Wb,       // [E, OUT_DIM, IN_DIM] bf16 (ws)
    const float* __restrict__ gates,    // [S] fp32
    const int*   __restrict__ kptr,
    const int*   __restrict__ ssi_raw,  // int32 or int64
    const int*   __restrict__ eoff_raw, // int32 or int64
    float*       __restrict__ out)      // [N_TOKENS, OUT_DIM] fp32
{
  // staging: A stages [0,24576), B stages [24576,49152) u16 (96 KB total);
  // epilogue aliases the full 128 KB as Cs[256][256] bf16.
  __shared__ __align__(16) u16 smem[BM * BN];

  const bool is64 = (eoff_raw[7] != S_SLOTS);
  const int tile = (blockIdx.x % NXCD) * CPX + blockIdx.x / NXCD;
  int expert, rs, re;
  if (!derive_tile(eoff_raw, is64, tile, BM, expert, rs, re)) return;

  const int n0   = blockIdx.y * BN;
  const int kdiv = kptr[0];
  const int t    = threadIdx.x;

  // --- staging sources: tile = 256 rows x 4 chunks of 16B = 1024 chunks.
  // chunk q = t + 512*j -> row q>>2, phys slot q&3, holding logical chunk
  // (q&3)^(row&3).  LDS dest stays linear (gload_lds requirement).
  const u16* asrc[2];
  const u16* bsrc[2];
#pragma unroll
  for (int j = 0; j < 2; ++j) {
    int q = t + 512 * j;
    int row = q >> 2, cphys = q & 3;
    int clog = cphys ^ (row & 3);
    int g = rs + row; if (g >= re) g = re - 1;
    int sv  = is64 ? ssi_raw[2 * g] : ssi_raw[g];
    int tok = sv / kdiv;
    asrc[j] = Xb + (size_t)tok * IN_DIM + clog * 8;
    bsrc[j] = Wb + ((size_t)expert * OUT_DIM + n0 + row) * IN_DIM + clog * 8;
  }

  f32x4 acc[8][4];
#pragma unroll
  for (int i = 0; i < 8; ++i)
#pragma unroll
    for (int j = 0; j < 4; ++j)
      acc[i][j] = (f32x4){0.f, 0.f, 0.f, 0.f};

  const int wave = t >> 6;
  const int lane = t & 63;
  const int wm = (wave >> 2) * 128;      // 2 M-wave rows
  const int wn = (wave & 3) * 64;        // 4 N-wave cols
  const int lr = lane & 15;
  const int hk = lane >> 4;              // 16B k-chunk selector (0..3)
  const int ck = ((hk ^ (lr & 3)) << 3); // swizzled chunk u16-offset (row&3==lr&3)

  // ---- prologue: issue stages for tiles 0 and 1 (no wait) ----
#pragma unroll
  for (int pt = 0; pt < 2; ++pt)
#pragma unroll
    for (int j = 0; j < 2; ++j) {
      GLD_LDS16(asrc[j] + pt * BK, ABUF(pt) + (size_t)(t + 512 * j) * 8);
      GLD_LDS16(bsrc[j] + pt * BK, BBUF(pt) + (size_t)(t + 512 * j) * 8);
    }

  for (int kt = 0; kt < NKT; ++kt) {
    const int cs = kt % 3;
    // --- issue tile kt+2 into stage (kt+2)%3, then counted wait ---
    if (kt + 2 < NKT) {
      const int ns = (kt + 2) % 3;
#pragma unroll
      for (int j = 0; j < 2; ++j) {
        GLD_LDS16(asrc[j] + (kt + 2) * BK, ABUF(ns) + (size_t)(t + 512 * j) * 8);
        GLD_LDS16(bsrc[j] + (kt + 2) * BK, BBUF(ns) + (size_t)(t + 512 * j) * 8);
      }
      asm volatile("s_waitcnt vmcnt(8)" ::: "memory");   // tile kt landed
    } else if (kt + 1 < NKT) {
      asm volatile("s_waitcnt vmcnt(4)" ::: "memory");
    } else {
      asm volatile("s_waitcnt vmcnt(0)" ::: "memory");
    }
    __builtin_amdgcn_s_barrier();        // all waves: tile kt fully in LDS

    const u16* Ab = ABUF(cs);
    const u16* Bb = BBUF(cs);
    short8 bfr[4];
#pragma unroll
    for (int ni = 0; ni < 4; ++ni)
      bfr[ni] = *(const short8*)&Bb[(wn + ni * 16 + lr) * BK + ck];
    short8 af[8];
#pragma unroll
    for (int mi = 0; mi < 8; ++mi)
      af[mi] = *(const short8*)&Ab[(wm + mi * 16 + lr) * BK + ck];
    asm volatile("s_waitcnt lgkmcnt(0)" ::: "memory");
    __builtin_amdgcn_sched_barrier(0);   // rule 18: pin MFMA after the wait
    __builtin_amdgcn_s_setprio(1);
#pragma unroll
    for (int mi = 0; mi < 8; ++mi)
#pragma unroll
      for (int ni = 0; ni < 4; ++ni)
        acc[mi][ni] = __builtin_amdgcn_mfma_f32_16x16x32_bf16(
            af[mi], bfr[ni], acc[mi][ni], 0, 0, 0);
    __builtin_amdgcn_s_setprio(0);
    __builtin_amdgcn_s_barrier();        // reads of stage cs done (WAR guard)
  }

  // ---- Epilogue 1: repack C (col=lane&15, row=(lane>>4)*4+reg) into Cs ----
  u16* Cs = smem;    // aliases staging buffers (final barrier above)
#pragma unroll
  for (int mi = 0; mi < 8; ++mi)
#pragma unroll
    for (int ni = 0; ni < 4; ++ni)
#pragma unroll
      for (int r = 0; r < 4; ++r) {
        int row = wm + mi * 16 + (lane >> 4) * 4 + r;
        int col = wn + ni * 16 + lr;
        Cs[row * BN + col] = f2bf(acc[mi][ni][r]);
      }
  __syncthreads();

  // ---- Epilogue 2: gate-combine complete pairs, plain fp32 stores --------
  const int s0     = rs + (rs & 1);        // first even slot in tile
  const int npairs = (re > s0) ? ((re - s0) >> 1) : 0;
  for (int it = t; it < npairs * 32; it += 512) {
    int p  = it >> 5;
    int cc = (it & 31) * 8;
    int lr0 = (s0 - rs) + 2 * p;           // local row of even slot
    float ga = gates[s0 + 2 * p];
    float gb = gates[s0 + 2 * p + 1];
    short8 c0 = *(const short8*)&Cs[lr0 * BN + cc];
    short8 c1 = *(const short8*)&Cs[(lr0 + 1) * BN + cc];
    f32x4 o0, o1;
#pragma unroll
    for (int j = 0; j < 4; ++j) {
      o0[j] = ga * bf2f((u16)c0[j])     + gb * bf2f((u16)c1[j]);
      o1[j] = ga * bf2f((u16)c0[4 + j]) + gb * bf2f((u16)c1[4 + j]);
    }
    float* dst = out + (size_t)((s0 + 2 * p) >> 1) * OUT_DIM + n0 + cc;
    *(f32x4*)dst       = o0;
    *((f32x4*)dst + 1) = o1;
  }

  // ---- Epilogue 3: edge rows (partner slot outside tile) -> atomicAdd ----
  if (rs & 1) {            // local row 0 = slot rs (odd), token rs>>1
    float g = gates[rs];
    float* dst = out + (size_t)(rs >> 1) * OUT_DIM + n0;
    for (int c = t; c < BN; c += 512)
      atomicAdd(dst + c, g * bf2f(Cs[c]));
  }
  if (re & 1) {            // last row = slot re-1 (even), partner re outside
    int lrow = re - 1 - rs;
    float g = gates[re - 1];
    float* dst = out + (size_t)((re - 1) >> 1) * OUT_DIM + n0;
    for (int c = t; c < BN; c += 512)
      atomicAdd(dst + c, g * bf2f(Cs[lrow * BN + c]));
  }
}

// ---------------------------------------------------------------------------
// Last-resort fallback (verified): fp32 staging + inline convert + atomics.
// Only used if the workspace is too small.  128-row tiles, own grid.
// ---------------------------------------------------------------------------
__global__ __launch_bounds__(256) void moe_gemm_fused_f32(
    const float* __restrict__ X, const float* __restrict__ W,
    const float* __restrict__ gates, const int* __restrict__ kptr,
    const int*   __restrict__ ssi_raw, const int* __restrict__ eoff_raw,
    float*       __restrict__ out)
{
  __shared__ __align__(16) u16 As[FBM * 32];
  __shared__ __align__(16) u16 Bs[FBM * 32];

  const bool is64 = (eoff_raw[7] != S_SLOTS);
  int expert, rs, re;
  if (!derive_tile(eoff_raw, is64, blockIdx.x, FBM, expert, rs, re)) return;
  const int rcount = re - rs;

  const int n0   = blockIdx.y * 128;
  const int kdiv = kptr[0];
  const int t    = threadIdx.x;

  const float* arow[4];
  const float* brow[4];
  int lofs[4];
#pragma unroll
  for (int i = 0; i < 4; ++i) {
    int c = t + 256 * i;
    int r = c >> 3;
    int col4 = (c & 7) * 4;
    int g = rs + r; if (g >= re) g = re - 1;
    int sval = is64 ? ssi_raw[2 * g] : ssi_raw[g];
    int tok  = sval / kdiv;
    arow[i] = X + (size_t)tok * IN_DIM + col4;
    brow[i] = W + ((size_t)expert * OUT_DIM + n0 + r) * IN_DIM + col4;
    lofs[i] = r * 32 + col4;
  }

  f32x4 acc[4][4];
#pragma unroll
  for (int i = 0; i < 4; ++i)
#pragma unroll
    for (int j = 0; j < 4; ++j)
      acc[i][j] = (f32x4){0.f, 0.f, 0.f, 0.f};

  const int wave = t >> 6;
  const int lane = t & 63;
  const int wm = (wave >> 1) * 64;
  const int wn = (wave & 1) * 64;
  const int lr = lane & 15;
  const int lk = (lane >> 4) * 8;

  for (int k0 = 0; k0 < IN_DIM; k0 += 32) {
    f32x4 a[4], b[4];
#pragma unroll
    for (int i = 0; i < 4; ++i) {
      a[i] = *(const f32x4*)(arow[i] + k0);
      b[i] = *(const f32x4*)(brow[i] + k0);
    }
    __syncthreads();
#pragma unroll
    for (int i = 0; i < 4; ++i) {
      short4v av, bv;
#pragma unroll
      for (int j = 0; j < 4; ++j) {
        av[j] = (short)f2bf(a[i][j]);
        bv[j] = (short)f2bf(b[i][j]);
      }
      *(short4v*)&As[lofs[i]] = av;
      *(short4v*)&Bs[lofs[i]] = bv;
    }
    __syncthreads();

    short8 af[4], bfv[4];
#pragma unroll
    for (int mi = 0; mi < 4; ++mi)
      af[mi] = *(const short8*)&As[(wm + mi * 16 + lr) * 32 + lk];
#pragma unroll
    for (int ni = 0; ni < 4; ++ni)
      bfv[ni] = *(const short8*)&Bs[(wn + ni * 16 + lr) * 32 + lk];

#pragma unroll
    for (int mi = 0; mi < 4; ++mi)
#pragma unroll
      for (int ni = 0; ni < 4; ++ni)
        acc[mi][ni] = __builtin_amdgcn_mfma_f32_16x16x32_bf16(
            af[mi], bfv[ni], acc[mi][ni], 0, 0, 0);
  }

#pragma unroll
  for (int mi = 0; mi < 4; ++mi) {
#pragma unroll
    for (int r = 0; r < 4; ++r) {
      int row = wm + mi * 16 + (lane >> 4) * 4 + r;
      if (row < rcount) {
        int slot  = rs + row;
        int token = slot / kdiv;
        float g   = gates[slot];
        float* dst = out + (size_t)token * OUT_DIM + n0;
#pragma unroll
        for (int ni = 0; ni < 4; ++ni) {
          int col = wn + ni * 16 + lr;
          atomicAdd(dst + col, g * acc[mi][ni][r]);
        }
      }
    }
  }
}

// ---------------------------------------------------------------------------
extern "C" void kernel_launch(void* const* d_in, const int* in_sizes, int n_in,
                              void* d_out, int out_size, void* d_ws, size_t ws_size,
                              hipStream_t stream) {
  const float* X     = (const float*)d_in[0];
  const float* W     = (const float*)d_in[1];
  const float* gates = (const float*)d_in[2];
  const int*   kptr  = (const int*)d_in[3];
  // d_in[4] = sorted_expert_idxs (unused; experts derived from offsets)
  const int*   ssi   = (const int*)d_in[5];
  const int*   eoff  = (const int*)d_in[6];
  float* out = (float*)d_out;

  const size_t x_elems = (size_t)N_TOKENS * IN_DIM;            // 16.7M
  const size_t w_elems = (size_t)N_EXPERTS * OUT_DIM * IN_DIM; // 8.4M
  const size_t need = (x_elems + w_elems) * sizeof(u16);       // 50 MB

  if (ws_size >= need) {
    u16* Xb = (u16*)d_ws;
    u16* Wb = Xb + x_elems;
    const int xn8 = (int)(x_elems / 8), wn8 = (int)(w_elems / 8);
    const int xblocks = (xn8 + 255) / 256, wblocks = (wn8 + 255) / 256;
    hipLaunchKernelGGL(convert_zero, dim3(xblocks + wblocks + MT),
                       dim3(256), 0, stream, X, W, Xb, Wb, eoff, out,
                       xblocks, wblocks, xn8, wn8);
    hipLaunchKernelGGL(moe_gemm_256, dim3(MT, NG), dim3(512),
                       0, stream, Xb, Wb, gates, kptr, ssi, eoff, out);
  } else {
    hipMemsetAsync(d_out, 0, (size_t)out_size * sizeof(float), stream);
    hipLaunchKernelGGL(moe_gemm_fused_f32, dim3(FMT, 8), dim3(256),
                       0, stream, X, W, gates, kptr, ssi, eoff, out);
  }
}

// Round 6
// 254.798 us; speedup vs baseline: 1.0179x; 1.0179x over previous
//
#include <hip/hip_runtime.h>
#include <stdint.h>

#define N_EXPERTS 8
#define IN_DIM    1024
#define OUT_DIM   1024
#define N_TOKENS  16384
#define S_SLOTS   (N_TOKENS * 2)

// ---- main 256x256 8-phase GEMM geometry ----
#define BM   256
#define BN   256
#define BK   64                    // bf16 K-cols per K-tile
#define NKT  (IN_DIM / BK)         // 16 K-tiles
#define MT   136                   // sum ceil(cnt_e/256) <= 128 + 8
#define NG   (OUT_DIM / BN)        // 4
#define NXCD 8
#define CPX  (MT / NXCD)           // 17 exact -> bijective XCD swizzle
// half-tile slots: A[(buf*2+h)] at smem + slot*8192 u16; B at +32768
#define ASLOT(b, h) (smem + ((b) * 2 + (h)) * 8192)
#define BSLOT(b, h) (smem + 32768 + ((b) * 2 + (h)) * 8192)

// ---- fallback geometry (verified legacy path) ----
#define FBM  128
#define FMT  264

typedef unsigned short u16;
using short4v = __attribute__((ext_vector_type(4))) short;
using short8  = __attribute__((ext_vector_type(8))) short;
using f32x4   = __attribute__((ext_vector_type(4))) float;

__device__ __forceinline__ u16 f2bf(float f) {
  uint32_t x = __builtin_bit_cast(uint32_t, f);
  uint32_t r = x + 0x7fffu + ((x >> 16) & 1u);   // round-to-nearest-even
  return (u16)(r >> 16);
}
__device__ __forceinline__ float bf2f(u16 u) {
  uint32_t x = ((uint32_t)u) << 16;
  return __builtin_bit_cast(float, x);
}

#define GLD_LDS16(g, l) __builtin_amdgcn_global_load_lds(            \
    (const __attribute__((address_space(1))) void*)(g),              \
    (__attribute__((address_space(3))) void*)(l), 16, 0, 0)

template <int W>
__device__ __forceinline__ void vmc() {
  if constexpr (W == 6)      asm volatile("s_waitcnt vmcnt(6)" ::: "memory");
  else if constexpr (W == 4) asm volatile("s_waitcnt vmcnt(4)" ::: "memory");
  else if constexpr (W == 2) asm volatile("s_waitcnt vmcnt(2)" ::: "memory");
  else                       asm volatile("s_waitcnt vmcnt(0)" ::: "memory");
}

// ---------------------------------------------------------------------------
// Shared tile derivation (slots sorted by expert), parametric block-M.
// ---------------------------------------------------------------------------
__device__ __forceinline__ bool derive_tile(const int* eoff_raw, bool is64,
                                            int bx, int bm,
                                            int& expert, int& rs, int& re) {
  int rem = bx, prev = 0;
  expert = -1;
  for (int e = 0; e < N_EXPERTS; ++e) {
    int end = is64 ? eoff_raw[2 * e] : eoff_raw[e];
    int cnt = end - prev;
    int nt  = (cnt + bm - 1) / bm;
    if (expert < 0) {
      if (rem < nt) {
        expert = e;
        rs = prev + rem * bm;
        re = (rs + bm < end) ? (rs + bm) : end;
      } else {
        rem -= nt;
      }
    }
    prev = end;
  }
  return expert >= 0;
}

// ---------------------------------------------------------------------------
// Node 1: fp32->bf16 convert of X and W, PLUS zeroing of straddle-pair token
// rows (odd 256-tile starts) so the GEMM can atomicAdd edge contributions.
// ---------------------------------------------------------------------------
__global__ __launch_bounds__(256) void convert_zero(
    const float* __restrict__ X, const float* __restrict__ W,
    u16* __restrict__ Xb, u16* __restrict__ Wb,
    const int* __restrict__ eoff_raw,
    float* __restrict__ out,
    int xblocks, int wblocks, int xn8, int wn8) {
  int bx = blockIdx.x;
  if (bx < xblocks + wblocks) {
    const float* src; u16* dst; int i, n8;
    if (bx < xblocks) { i = bx * 256 + threadIdx.x; src = X; dst = Xb; n8 = xn8; }
    else { i = (bx - xblocks) * 256 + threadIdx.x; src = W; dst = Wb; n8 = wn8; }
    if (i >= n8) return;
    const f32x4* s = (const f32x4*)src + (size_t)i * 2;
    f32x4 v0 = s[0], v1 = s[1];
    short8 o;
#pragma unroll
    for (int j = 0; j < 4; ++j) {
      o[j]     = (short)f2bf(v0[j]);
      o[4 + j] = (short)f2bf(v1[j]);
    }
    *(short8*)(dst + (size_t)i * 8) = o;
  } else {
    int bx2 = bx - xblocks - wblocks;
    const bool is64 = (eoff_raw[7] != S_SLOTS);
    int expert, rs, re;
    if (!derive_tile(eoff_raw, is64, bx2, BM, expert, rs, re)) return;
    if (rs & 1) {
      f32x4 z = (f32x4){0.f, 0.f, 0.f, 0.f};
      *(f32x4*)(out + (size_t)(rs >> 1) * OUT_DIM + threadIdx.x * 4) = z;
    }
  }
}

// ---------------------------------------------------------------------------
// Node 2: 256x256 grouped GEMM, 8-phase + counted-vmcnt schedule (T3+T4+T5):
//  - K-tile BK=64; staging granule = HALF-TILE (128 rows x 64 cols, 16 KB);
//    4 slots/operand (2dbuf x 2half, 128 KB total), global_load_lds with
//    source-pre-swizzled addresses (linear LDS dest, rule 21/m173).
//  - 4 phases per K-tile; phase Q: issue ONE half-tile of tile kt+1 (2 GLD)
//    -> vmcnt(6) [exactly 3 newer half-tiles outstanding; half first used
//    this phase is guaranteed landed; NEVER 0 in the loop] -> s_barrier
//    [publishes all waves' staging] -> 12 ds_read (swizzled, conflict-free)
//    -> lgkmcnt(0)+sched_barrier -> setprio(1) -> 16 MFMA (one 128x128
//    C-quadrant, all 8 waves) -> setprio(0) -> s_barrier.
//  - quadrant Q: (mh,nh) = (Q&1, Q>>1); wave w covers rows (w>>2)*64,
//    cols (w&3)*32 of the quadrant.  Issue order A0,B0,A1,B1 matches.
// Epilogue: proven LDS repack + gate-combine pairs + atomicAdd edges.
// ---------------------------------------------------------------------------
__global__ __launch_bounds__(512, 2) void moe_gemm_256(
    const u16*   __restrict__ Xb,       // [N_TOKENS, IN_DIM] bf16 (ws)
    const u16*   __restrict__ Wb,       // [E, OUT_DIM, IN_DIM] bf16 (ws)
    const float* __restrict__ gates,    // [S] fp32
    const int*   __restrict__ kptr,
    const int*   __restrict__ ssi_raw,  // int32 or int64
    const int*   __restrict__ eoff_raw, // int32 or int64
    float*       __restrict__ out)      // [N_TOKENS, OUT_DIM] fp32
{
  __shared__ __align__(16) u16 smem[BM * BN];   // 128 KB; Cs aliases all

  const bool is64 = (eoff_raw[7] != S_SLOTS);
  const int tile = (blockIdx.x % NXCD) * CPX + blockIdx.x / NXCD;
  int expert, rs, re;
  if (!derive_tile(eoff_raw, is64, tile, BM, expert, rs, re)) return;

  const int n0   = blockIdx.y * BN;
  const int kdiv = kptr[0];
  const int t    = threadIdx.x;

  // --- staging sources per (half h, unit j): unit u = t + 512*j of the
  // half-tile (1024 16B units): lrow = u>>3, cphys = u&7, holding logical
  // chunk clog = cphys ^ (lrow&7) -> LDS ends up swizzled, dest linear.
  const u16* aptr[2][2];
  const u16* bptr[2][2];
#pragma unroll
  for (int h = 0; h < 2; ++h)
#pragma unroll
    for (int j = 0; j < 2; ++j) {
      int u = t + 512 * j;
      int lrow = u >> 3, cphys = u & 7;
      int clog = cphys ^ (lrow & 7);
      int g = rs + h * 128 + lrow; if (g >= re) g = re - 1;
      int sv  = is64 ? ssi_raw[2 * g] : ssi_raw[g];
      int tok = sv / kdiv;
      aptr[h][j] = Xb + (size_t)tok * IN_DIM + clog * 8;
      bptr[h][j] = Wb + ((size_t)expert * OUT_DIM + n0 + h * 128 + lrow) * IN_DIM
                   + clog * 8;
    }
  const int ldsu0 = t * 8;              // u16 offset of unit j=0
  const int ldsu1 = (t + 512) * 8;      // unit j=1

  // acc[q][mi2][ni2]: quadrant q=(mh,nh), wave-subtile 64x32 -> 4x2 frags
  f32x4 acc[4][4][2];
#pragma unroll
  for (int q = 0; q < 4; ++q)
#pragma unroll
    for (int i = 0; i < 4; ++i)
#pragma unroll
      for (int j = 0; j < 2; ++j)
        acc[q][i][j] = (f32x4){0.f, 0.f, 0.f, 0.f};

  const int wave = t >> 6;
  const int lane = t & 63;
  const int wr64 = (wave >> 2) * 64;     // row base within quadrant
  const int wc32 = (wave & 3) * 32;      // col base within quadrant
  const int lr = lane & 15;
  const int hk = lane >> 4;              // k-chunk selector within K=32

  // ---- prologue: issue tile 0's four half-tiles (A0,B0,A1,B1) ----
#pragma unroll
  for (int h = 0; h < 2; ++h) {
    GLD_LDS16(aptr[h][0], ASLOT(0, h) + ldsu0);
    GLD_LDS16(aptr[h][1], ASLOT(0, h) + ldsu1);
    GLD_LDS16(bptr[h][0], BSLOT(0, h) + ldsu0);
    GLD_LDS16(bptr[h][1], BSLOT(0, h) + ldsu1);
  }

  for (int kt = 0; kt < NKT; ++kt) {
    const int cb = kt & 1, nb = cb ^ 1;
    const int kn = (kt + 1) * BK;        // next tile K offset (u16 elems)
    const bool last = (kt == NKT - 1);

    // helper lambdas expressed inline per phase (unrolled by hand):
#define PHASE(Q, ISSUE_STMT, WSTEADY, WLAST)                                   \
    {                                                                          \
      if (!last) { ISSUE_STMT; }                                               \
      if (!last) vmc<WSTEADY>(); else vmc<WLAST>();                            \
      __builtin_amdgcn_s_barrier();                                            \
      __builtin_amdgcn_sched_barrier(0);                                       \
      const int mh = (Q) & 1, nh = (Q) >> 1;                                   \
      const u16* Ab = ASLOT(cb, mh);                                           \
      const u16* Bb = BSLOT(cb, nh);                                           \
      short8 af[4][2], bf[2][2];                                               \
      _Pragma("unroll")                                                        \
      for (int mi = 0; mi < 4; ++mi) {                                         \
        int lrow = wr64 + mi * 16 + lr;                                        \
        _Pragma("unroll")                                                      \
        for (int kk = 0; kk < 2; ++kk) {                                       \
          int cl = kk * 4 + hk;                                                \
          af[mi][kk] = *(const short8*)&Ab[lrow * 64 +                         \
                                           ((cl ^ (lrow & 7)) << 3)];          \
        }                                                                      \
      }                                                                        \
      _Pragma("unroll")                                                        \
      for (int ni = 0; ni < 2; ++ni) {                                         \
        int lrow = wc32 + ni * 16 + lr;                                        \
        _Pragma("unroll")                                                      \
        for (int kk = 0; kk < 2; ++kk) {                                       \
          int cl = kk * 4 + hk;                                                \
          bf[ni][kk] = *(const short8*)&Bb[lrow * 64 +                         \
                                           ((cl ^ (lrow & 7)) << 3)];          \
        }                                                                      \
      }                                                                        \
      asm volatile("s_waitcnt lgkmcnt(0)" ::: "memory");                       \
      __builtin_amdgcn_sched_barrier(0);                                       \
      __builtin_amdgcn_s_setprio(1);                                           \
      _Pragma("unroll")                                                        \
      for (int mi = 0; mi < 4; ++mi)                                           \
        _Pragma("unroll")                                                      \
        for (int ni = 0; ni < 2; ++ni)                                         \
          _Pragma("unroll")                                                    \
          for (int kk = 0; kk < 2; ++kk)                                       \
            acc[Q][mi][ni] = __builtin_amdgcn_mfma_f32_16x16x32_bf16(          \
                af[mi][kk], bf[ni][kk], acc[Q][mi][ni], 0, 0, 0);              \
      __builtin_amdgcn_s_setprio(0);                                           \
      __builtin_amdgcn_s_barrier();                                            \
    }

    PHASE(0,
          { GLD_LDS16(aptr[0][0] + kn, ASLOT(nb, 0) + ldsu0);
            GLD_LDS16(aptr[0][1] + kn, ASLOT(nb, 0) + ldsu1); }, 6, 4)
    PHASE(1,
          { GLD_LDS16(bptr[0][0] + kn, BSLOT(nb, 0) + ldsu0);
            GLD_LDS16(bptr[0][1] + kn, BSLOT(nb, 0) + ldsu1); }, 6, 2)
    PHASE(2,
          { GLD_LDS16(aptr[1][0] + kn, ASLOT(nb, 1) + ldsu0);
            GLD_LDS16(aptr[1][1] + kn, ASLOT(nb, 1) + ldsu1); }, 6, 0)
    PHASE(3,
          { GLD_LDS16(bptr[1][0] + kn, BSLOT(nb, 1) + ldsu0);
            GLD_LDS16(bptr[1][1] + kn, BSLOT(nb, 1) + ldsu1); }, 6, 0)
#undef PHASE
  }

  // ---- Epilogue 1: repack C (col=lane&15, row=(lane>>4)*4+reg) into Cs ----
  u16* Cs = smem;    // aliases staging (final phase barrier above)
#pragma unroll
  for (int q = 0; q < 4; ++q)
#pragma unroll
    for (int mi = 0; mi < 4; ++mi)
#pragma unroll
      for (int ni = 0; ni < 2; ++ni)
#pragma unroll
        for (int r = 0; r < 4; ++r) {
          int row = (q & 1) * 128 + wr64 + mi * 16 + (lane >> 4) * 4 + r;
          int col = (q >> 1) * 128 + wc32 + ni * 16 + lr;
          Cs[row * BN + col] = f2bf(acc[q][mi][ni][r]);
        }
  __syncthreads();

  // ---- Epilogue 2: gate-combine complete pairs, plain fp32 stores --------
  const int s0     = rs + (rs & 1);        // first even slot in tile
  const int npairs = (re > s0) ? ((re - s0) >> 1) : 0;
  for (int it = t; it < npairs * 32; it += 512) {
    int p  = it >> 5;
    int cc = (it & 31) * 8;
    int lr0 = (s0 - rs) + 2 * p;           // local row of even slot
    float ga = gates[s0 + 2 * p];
    float gb = gates[s0 + 2 * p + 1];
    short8 c0 = *(const short8*)&Cs[lr0 * BN + cc];
    short8 c1 = *(const short8*)&Cs[(lr0 + 1) * BN + cc];
    f32x4 o0, o1;
#pragma unroll
    for (int j = 0; j < 4; ++j) {
      o0[j] = ga * bf2f((u16)c0[j])     + gb * bf2f((u16)c1[j]);
      o1[j] = ga * bf2f((u16)c0[4 + j]) + gb * bf2f((u16)c1[4 + j]);
    }
    float* dst = out + (size_t)((s0 + 2 * p) >> 1) * OUT_DIM + n0 + cc;
    *(f32x4*)dst       = o0;
    *((f32x4*)dst + 1) = o1;
  }

  // ---- Epilogue 3: edge rows (partner slot outside tile) -> atomicAdd ----
  if (rs & 1) {            // local row 0 = slot rs (odd), token rs>>1
    float g = gates[rs];
    float* dst = out + (size_t)(rs >> 1) * OUT_DIM + n0;
    for (int c = t; c < BN; c += 512)
      atomicAdd(dst + c, g * bf2f(Cs[c]));
  }
  if (re & 1) {            // last row = slot re-1 (even), partner re outside
    int lrow = re - 1 - rs;
    float g = gates[re - 1];
    float* dst = out + (size_t)((re - 1) >> 1) * OUT_DIM + n0;
    for (int c = t; c < BN; c += 512)
      atomicAdd(dst + c, g * bf2f(Cs[lrow * BN + c]));
  }
}

// ---------------------------------------------------------------------------
// Last-resort fallback (verified): fp32 staging + inline convert + atomics.
// Only used if the workspace is too small.  128-row tiles, own grid.
// ---------------------------------------------------------------------------
__global__ __launch_bounds__(256) void moe_gemm_fused_f32(
    const float* __restrict__ X, const float* __restrict__ W,
    const float* __restrict__ gates, const int* __restrict__ kptr,
    const int*   __restrict__ ssi_raw, const int* __restrict__ eoff_raw,
    float*       __restrict__ out)
{
  __shared__ __align__(16) u16 As[FBM * 32];
  __shared__ __align__(16) u16 Bs[FBM * 32];

  const bool is64 = (eoff_raw[7] != S_SLOTS);
  int expert, rs, re;
  if (!derive_tile(eoff_raw, is64, blockIdx.x, FBM, expert, rs, re)) return;
  const int rcount = re - rs;

  const int n0   = blockIdx.y * 128;
  const int kdiv = kptr[0];
  const int t    = threadIdx.x;

  const float* arow[4];
  const float* brow[4];
  int lofs[4];
#pragma unroll
  for (int i = 0; i < 4; ++i) {
    int c = t + 256 * i;
    int r = c >> 3;
    int col4 = (c & 7) * 4;
    int g = rs + r; if (g >= re) g = re - 1;
    int sval = is64 ? ssi_raw[2 * g] : ssi_raw[g];
    int tok  = sval / kdiv;
    arow[i] = X + (size_t)tok * IN_DIM + col4;
    brow[i] = W + ((size_t)expert * OUT_DIM + n0 + r) * IN_DIM + col4;
    lofs[i] = r * 32 + col4;
  }

  f32x4 acc[4][4];
#pragma unroll
  for (int i = 0; i < 4; ++i)
#pragma unroll
    for (int j = 0; j < 4; ++j)
      acc[i][j] = (f32x4){0.f, 0.f, 0.f, 0.f};

  const int wave = t >> 6;
  const int lane = t & 63;
  const int wm = (wave >> 1) * 64;
  const int wn = (wave & 1) * 64;
  const int lr = lane & 15;
  const int lk = (lane >> 4) * 8;

  for (int k0 = 0; k0 < IN_DIM; k0 += 32) {
    f32x4 a[4], b[4];
#pragma unroll
    for (int i = 0; i < 4; ++i) {
      a[i] = *(const f32x4*)(arow[i] + k0);
      b[i] = *(const f32x4*)(brow[i] + k0);
    }
    __syncthreads();
#pragma unroll
    for (int i = 0; i < 4; ++i) {
      short4v av, bv;
#pragma unroll
      for (int j = 0; j < 4; ++j) {
        av[j] = (short)f2bf(a[i][j]);
        bv[j] = (short)f2bf(b[i][j]);
      }
      *(short4v*)&As[lofs[i]] = av;
      *(short4v*)&Bs[lofs[i]] = bv;
    }
    __syncthreads();

    short8 af[4], bfv[4];
#pragma unroll
    for (int mi = 0; mi < 4; ++mi)
      af[mi] = *(const short8*)&As[(wm + mi * 16 + lr) * 32 + lk];
#pragma unroll
    for (int ni = 0; ni < 4; ++ni)
      bfv[ni] = *(const short8*)&Bs[(wn + ni * 16 + lr) * 32 + lk];

#pragma unroll
    for (int mi = 0; mi < 4; ++mi)
#pragma unroll
      for (int ni = 0; ni < 4; ++ni)
        acc[mi][ni] = __builtin_amdgcn_mfma_f32_16x16x32_bf16(
            af[mi], bfv[ni], acc[mi][ni], 0, 0, 0);
  }

#pragma unroll
  for (int mi = 0; mi < 4; ++mi) {
#pragma unroll
    for (int r = 0; r < 4; ++r) {
      int row = wm + mi * 16 + (lane >> 4) * 4 + r;
      if (row < rcount) {
        int slot  = rs + row;
        int token = slot / kdiv;
        float g   = gates[slot];
        float* dst = out + (size_t)token * OUT_DIM + n0;
#pragma unroll
        for (int ni = 0; ni < 4; ++ni) {
          int col = wn + ni * 16 + lr;
          atomicAdd(dst + col, g * acc[mi][ni][r]);
        }
      }
    }
  }
}

// ---------------------------------------------------------------------------
extern "C" void kernel_launch(void* const* d_in, const int* in_sizes, int n_in,
                              void* d_out, int out_size, void* d_ws, size_t ws_size,
                              hipStream_t stream) {
  const float* X     = (const float*)d_in[0];
  const float* W     = (const float*)d_in[1];
  const float* gates = (const float*)d_in[2];
  const int*   kptr  = (const int*)d_in[3];
  // d_in[4] = sorted_expert_idxs (unused; experts derived from offsets)
  const int*   ssi   = (const int*)d_in[5];
  const int*   eoff  = (const int*)d_in[6];
  float* out = (float*)d_out;

  const size_t x_elems = (size_t)N_TOKENS * IN_DIM;            // 16.7M
  const size_t w_elems = (size_t)N_EXPERTS * OUT_DIM * IN_DIM; // 8.4M
  const size_t need = (x_elems + w_elems) * sizeof(u16);       // 50 MB

  if (ws_size >= need) {
    u16* Xb = (u16*)d_ws;
    u16* Wb = Xb + x_elems;
    const int xn8 = (int)(x_elems / 8), wn8 = (int)(w_elems / 8);
    const int xblocks = (xn8 + 255) / 256, wblocks = (wn8 + 255) / 256;
    hipLaunchKernelGGL(convert_zero, dim3(xblocks + wblocks + MT),
                       dim3(256), 0, stream, X, W, Xb, Wb, eoff, out,
                       xblocks, wblocks, xn8, wn8);
    hipLaunchKernelGGL(moe_gemm_256, dim3(MT, NG), dim3(512),
                       0, stream, Xb, Wb, gates, kptr, ssi, eoff, out);
  } else {
    hipMemsetAsync(d_out, 0, (size_t)out_size * sizeof(float), stream);
    hipLaunchKernelGGL(moe_gemm_fused_f32, dim3(FMT, 8), dim3(256),
                       0, stream, X, W, gates, kptr, ssi, eoff, out);
  }
}